// Round 9
// baseline (2620.430 us; speedup 1.0000x reference)
//
#include <hip/hip_runtime.h>
#include <stdint.h>

#define OUT_F 4096
#define IN_F  4096
#define NGROUPS 32
#define BK2 32
#define NT2 (IN_F / BK2)   // 128

typedef __attribute__((ext_vector_type(4)))  float    f32x4;
typedef __attribute__((ext_vector_type(8)))  short    bf16x8;
typedef __attribute__((ext_vector_type(4)))  int      i32x4;
typedef __attribute__((ext_vector_type(4)))  uint32_t u32x4;

__device__ __forceinline__ ushort f2bf(float f) {
  union { float f; uint32_t u; } v; v.f = f;
  uint32_t r = v.u + 0x7FFFu + ((v.u >> 16) & 1u);
  return (ushort)(r >> 16);
}

// ---- kernel 1: x (f32) -> bf16, 8 elems/thread --------------------------
__global__ void cvt_x_kernel(const float* __restrict__ x, ushort* __restrict__ xb, int n8) {
  int i = blockIdx.x * blockDim.x + threadIdx.x;
  if (i >= n8) return;
  const f32x4* xp = (const f32x4*)x;
  f32x4 a = xp[2 * i], b = xp[2 * i + 1];
  u32x4 o;
  o.x = (uint32_t)f2bf(a.x) | ((uint32_t)f2bf(a.y) << 16);
  o.y = (uint32_t)f2bf(a.z) | ((uint32_t)f2bf(a.w) << 16);
  o.z = (uint32_t)f2bf(b.x) | ((uint32_t)f2bf(b.y) << 16);
  o.w = (uint32_t)f2bf(b.z) | ((uint32_t)f2bf(b.w) << 16);
  ((u32x4*)xb)[i] = o;
}

// ---- kernel 2: dequant weight -> bf16 [OUT_F][IN_F] ----------------------
__global__ void dequant_w_kernel(const int* __restrict__ cw,
                                 const float* __restrict__ sc,
                                 const float* __restrict__ of,
                                 ushort* __restrict__ wb) {
  int t = blockIdx.x * blockDim.x + threadIdx.x;
  int o  = t >> 9;
  int k0 = (t & 511) << 3;
  int g  = k0 >> 7;
  float s   = sc[o * NGROUPS + g];
  float off = of[o * NGROUPS + g];
  const i32x4* cp = (const i32x4*)(cw + (size_t)o * IN_F + k0);
  i32x4 c0 = cp[0], c1 = cp[1];
  u32x4 out;
  out.x = (uint32_t)f2bf((float)c0.x * s - off) | ((uint32_t)f2bf((float)c0.y * s - off) << 16);
  out.y = (uint32_t)f2bf((float)c0.z * s - off) | ((uint32_t)f2bf((float)c0.w * s - off) << 16);
  out.z = (uint32_t)f2bf((float)c1.x * s - off) | ((uint32_t)f2bf((float)c1.y * s - off) << 16);
  out.w = (uint32_t)f2bf((float)c1.z * s - off) | ((uint32_t)f2bf((float)c1.w * s - off) << 16);
  *(u32x4*)(wb + (size_t)o * IN_F + k0) = out;
}

// ---- kernel 3: 256x256 tile, BK=32, 64KB LDS dbuf -> 2 BLOCKS/CU ---------
// C[M][N] = A[M][K] * B[N][K]^T, bf16 in, f32 out.
// LDS 64KB: [buf(2)][A 256x32 (16KB) | B 256x32 (16KB)], row = 64B = 4 x 16B slots.
// swizzle: slot_phys = slot_log ^ ((row>>1)&3) via pre-swizzled global source.
//   (bank check: per 16-lane phase, (frow parity x slot) covers all 8 bank-quads
//    with exactly 2 lanes each = balanced -> conflict-free b128.)
// Cross-block TLP does the latency hiding (m97/m114 mechanism): 2 independent
// blocks per CU, 4 waves/SIMD, so one block's MFMA bursts cover the other's
// read/stage windows. Schedule kept simple: counted-vmcnt 2-phase per K-tile.
// Ledger: prologue stages tiles 0,1 (8 units). Steady gate: outstanding =
// stage(t) 4 + stage(t+1) 4 -> vmcnt(4) retires t, keeps t+1 (age ~2 tiles).
// stage(t+2) -> cur buffer, issued only after lgkm0+BAR (all reads of t done).

#define BAR() do { asm volatile("" ::: "memory"); __builtin_amdgcn_s_barrier(); asm volatile("" ::: "memory"); } while (0)
#define LGKM0() asm volatile("s_waitcnt lgkmcnt(0)" ::: "memory")
#define VM4() asm volatile("s_waitcnt vmcnt(4)" ::: "memory")
#define VM0() asm volatile("s_waitcnt vmcnt(0)" ::: "memory")

#define GLLDS(gp, lp) __builtin_amdgcn_global_load_lds( \
  (const __attribute__((address_space(1))) uint32_t*)(const void*)(gp), \
  (__attribute__((address_space(3))) uint32_t*)(void*)(lp), 16, 0, 0)

// stage full K-tile (A 16KB + B 16KB = 4 units/lane)
#define STG(buf, kt) do { \
  GLLDS(A + (size_t)(m0 +       stRow) * IN_F + (kt) * BK2 + sl * 8, ldsb + (buf) * 32768 +         wid * 1024); \
  GLLDS(A + (size_t)(m0 + 128 + stRow) * IN_F + (kt) * BK2 + sl * 8, ldsb + (buf) * 32768 +  8192 + wid * 1024); \
  GLLDS(B + (size_t)(n0 +       stRow) * IN_F + (kt) * BK2 + sl * 8, ldsb + (buf) * 32768 + 16384 + wid * 1024); \
  GLLDS(B + (size_t)(n0 + 128 + stRow) * IN_F + (kt) * BK2 + sl * 8, ldsb + (buf) * 32768 + 24576 + wid * 1024); \
} while (0)

__global__ __launch_bounds__(512, 4) void gemm256(const ushort* __restrict__ A,
                                                  const ushort* __restrict__ B,
                                                  float* __restrict__ C, int M) {
  __shared__ ushort lds[32768];   // 64 KiB -> 2 blocks/CU
  char* ldsb = (char*)lds;

  const int nmt = M >> 8;
  const int nwg = gridDim.x;
  int wg = blockIdx.x;
  if ((nwg & 7) == 0) wg = (wg & 7) * (nwg >> 3) + (wg >> 3);   // XCD swizzle (bijective)
  const int bn = wg / nmt;
  const int bm = wg % nmt;
  const int m0 = bm << 8, n0 = bn << 8;

  const int tid  = threadIdx.x;
  const int lane = tid & 63;
  const int wid  = tid >> 6;
  const int wr   = wid >> 2;                 // A 128-row half
  const int wc   = wid & 3;                  // B 64-col stripe

  // staging geometry: sweep covers 128 rows; lane's 16B slot pre-swizzled
  const int stRow = tid >> 2;                            // 0..127
  const int sl    = (tid & 3) ^ ((tid >> 3) & 3);        // phys slot = log ^ ((row>>1)&3)

  // fragment geometry (16x16x32): row = lane&15, k-slot = lane>>4; swizzle
  // term ((row>>1)&3) is lane-constant since frag rows step by 16.
  const int frow = lane & 15;
  const int g    = lane >> 4;
  const int koff = ((g ^ ((frow >> 1) & 3)) << 4);

  f32x4 acc[8][4] = {};
  bf16x8 Af[8], Bf[4];

  // ---- prologue: stage tiles 0 and 1 (8 vmcnt units)
  STG(0, 0);
  STG(1, 1);

#pragma unroll 1
  for (int t = 0; t < NT2; ++t) {
    const int cur = t & 1;
    const char* aC = ldsb + cur * 32768;
    const char* bC = ldsb + cur * 32768 + 16384;

    // gate: stage(t) landed (own), then CU-wide
    if (t + 1 < NT2) VM4(); else VM0();
    BAR();

    // reads: 8 A-frags + 4 B-frags (b128, conflict-free)
#pragma unroll
    for (int i = 0; i < 8; ++i)
      Af[i] = *(const bf16x8*)(aC + (wr * 128 + i * 16 + frow) * 64 + koff);
#pragma unroll
    for (int j = 0; j < 4; ++j)
      Bf[j] = *(const bf16x8*)(bC + (wc * 64 + j * 16 + frow) * 64 + koff);
    LGKM0();
    BAR();   // all waves' reads of tile t done -> cur buffer free for t+2

    if (t + 2 < NT2) STG(cur, t + 2);

    __builtin_amdgcn_s_setprio(1);
#pragma unroll
    for (int i = 0; i < 8; ++i)
#pragma unroll
      for (int j = 0; j < 4; ++j)
        acc[i][j] = __builtin_amdgcn_mfma_f32_16x16x32_bf16(Af[i], Bf[j], acc[i][j], 0, 0, 0);
    __builtin_amdgcn_s_setprio(0);
  }

  // ---- epilogue: C/D layout col=lane&15, row=(lane>>4)*4+reg [m89-verified]
  const int crow0 = m0 + wr * 128 + (g << 2);
  const int ccol0 = n0 + wc * 64 + frow;
#pragma unroll
  for (int mf = 0; mf < 8; ++mf)
#pragma unroll
    for (int nf = 0; nf < 4; ++nf)
#pragma unroll
      for (int q = 0; q < 4; ++q)
        C[(size_t)(crow0 + mf * 16 + q) * OUT_F + (ccol0 + nf * 16)] = acc[mf][nf][q];
}

// ---- fallback: naive f32, correct but slow ------------------------------
__global__ void naive_kernel(const float* __restrict__ x, const int* __restrict__ cw,
                             const float* __restrict__ sc, const float* __restrict__ of,
                             float* __restrict__ out, int M) {
  int idx = blockIdx.x * blockDim.x + threadIdx.x;
  if (idx >= M * OUT_F) return;
  int o = idx & (OUT_F - 1);
  int m = idx >> 12;
  const float* xr = x + (size_t)m * IN_F;
  const int*   wr = cw + (size_t)o * IN_F;
  float acc = 0.f;
  for (int gg = 0; gg < NGROUPS; ++gg) {
    float s = sc[o * NGROUPS + gg], off = of[o * NGROUPS + gg];
#pragma unroll 8
    for (int k = 0; k < 128; ++k) {
      int kk = (gg << 7) + k;
      acc += xr[kk] * ((float)wr[kk] * s - off);
    }
  }
  out[idx] = acc;
}

extern "C" void kernel_launch(void* const* d_in, const int* in_sizes, int n_in,
                              void* d_out, int out_size, void* d_ws, size_t ws_size,
                              hipStream_t stream) {
  const float* x  = (const float*)d_in[0];
  const int*   cw = (const int*)d_in[1];
  const float* sc = (const float*)d_in[2];
  const float* of = (const float*)d_in[3];
  float* out = (float*)d_out;
  const int M = in_sizes[0] / IN_F;   // 8192

  const size_t xb_bytes = (size_t)M * IN_F * 2;
  const size_t wb_bytes = (size_t)OUT_F * IN_F * 2;

  if (ws_size >= xb_bytes + wb_bytes && (M % 256) == 0) {
    ushort* xb = (ushort*)d_ws;
    ushort* wb = (ushort*)((char*)d_ws + xb_bytes);

    int n8 = (M * IN_F) / 8;
    cvt_x_kernel<<<(n8 + 255) / 256, 256, 0, stream>>>(x, xb, n8);

    int nw8 = (OUT_F * IN_F) / 8;
    dequant_w_kernel<<<(nw8 + 255) / 256, 256, 0, stream>>>(cw, sc, of, wb);

    dim3 grid((M / 256) * (OUT_F / 256));   // 32 * 16 = 512 = 2 blocks/CU exactly
    gemm256<<<grid, 512, 0, stream>>>(xb, wb, out, M);
  } else {
    int total = M * OUT_F;
    naive_kernel<<<(total + 255) / 256, 256, 0, stream>>>(x, cw, sc, of, out, M);
  }
}

// Round 10
// 408.301 us; speedup vs baseline: 6.4179x; 6.4179x over previous
//
#include <hip/hip_runtime.h>
#include <stdint.h>

#define OUT_F 4096
#define IN_F  4096
#define NGROUPS 32
#define BK2 32
#define NT2 (IN_F / BK2)   // 128

typedef __attribute__((ext_vector_type(4)))  float    f32x4;
typedef __attribute__((ext_vector_type(8)))  short    bf16x8;
typedef __attribute__((ext_vector_type(4)))  int      i32x4;
typedef __attribute__((ext_vector_type(4)))  uint32_t u32x4;

__device__ __forceinline__ ushort f2bf(float f) {
  union { float f; uint32_t u; } v; v.f = f;
  uint32_t r = v.u + 0x7FFFu + ((v.u >> 16) & 1u);
  return (ushort)(r >> 16);
}

// ---- kernel 1: x (f32) -> bf16, 8 elems/thread --------------------------
__global__ void cvt_x_kernel(const float* __restrict__ x, ushort* __restrict__ xb, int n8) {
  int i = blockIdx.x * blockDim.x + threadIdx.x;
  if (i >= n8) return;
  const f32x4* xp = (const f32x4*)x;
  f32x4 a = xp[2 * i], b = xp[2 * i + 1];
  u32x4 o;
  o.x = (uint32_t)f2bf(a.x) | ((uint32_t)f2bf(a.y) << 16);
  o.y = (uint32_t)f2bf(a.z) | ((uint32_t)f2bf(a.w) << 16);
  o.z = (uint32_t)f2bf(b.x) | ((uint32_t)f2bf(b.y) << 16);
  o.w = (uint32_t)f2bf(b.z) | ((uint32_t)f2bf(b.w) << 16);
  ((u32x4*)xb)[i] = o;
}

// ---- kernel 2: dequant weight -> bf16 [OUT_F][IN_F] ----------------------
__global__ void dequant_w_kernel(const int* __restrict__ cw,
                                 const float* __restrict__ sc,
                                 const float* __restrict__ of,
                                 ushort* __restrict__ wb) {
  int t = blockIdx.x * blockDim.x + threadIdx.x;
  int o  = t >> 9;
  int k0 = (t & 511) << 3;
  int g  = k0 >> 7;
  float s   = sc[o * NGROUPS + g];
  float off = of[o * NGROUPS + g];
  const i32x4* cp = (const i32x4*)(cw + (size_t)o * IN_F + k0);
  i32x4 c0 = cp[0], c1 = cp[1];
  u32x4 out;
  out.x = (uint32_t)f2bf((float)c0.x * s - off) | ((uint32_t)f2bf((float)c0.y * s - off) << 16);
  out.y = (uint32_t)f2bf((float)c0.z * s - off) | ((uint32_t)f2bf((float)c0.w * s - off) << 16);
  out.z = (uint32_t)f2bf((float)c1.x * s - off) | ((uint32_t)f2bf((float)c1.y * s - off) << 16);
  out.w = (uint32_t)f2bf((float)c1.z * s - off) | ((uint32_t)f2bf((float)c1.w * s - off) << 16);
  *(u32x4*)(wb + (size_t)o * IN_F + k0) = out;
}

// ---- kernel 3: 256x128 tile, BK=32, 48KB LDS dbuf -> 2 BLOCKS/CU ---------
// C[M][N] = A[M][K] * B[N][K]^T, bf16 in, f32 out.
// 8 waves, each owns a 64x64 sub-tile (acc = 4x4 f32x4 = 64 VGPR; total regs
// ~115 < 128 cap of __launch_bounds__(512,4) -> NO SPILL, unlike R9).
// LDS 48KB: [buf(2)][A 256x32 (16KB) | B 128x32 (8KB)], row = 64B (4 x 16B slots).
// swizzle: slot_phys = slot_log ^ ((row>>1)&3), pre-swizzled global source
//   (R9-verified: absmax OK, SQ_LDS_BANK_CONFLICT = 0).
// Cross-block TLP hides latency (m97/m114): 2 independent blocks/CU, 4 waves/SIMD.
// Ledger: 3 stage-units/tile. Prologue 6 in flight. Gate vmcnt(3) retires
// stage(t), keeps stage(t+1); stage(t+2)->cur only after lgkm0+BAR.

#define BAR() do { asm volatile("" ::: "memory"); __builtin_amdgcn_s_barrier(); asm volatile("" ::: "memory"); } while (0)
#define LGKM0() asm volatile("s_waitcnt lgkmcnt(0)" ::: "memory")
#define VM3() asm volatile("s_waitcnt vmcnt(3)" ::: "memory")
#define VM0() asm volatile("s_waitcnt vmcnt(0)" ::: "memory")

#define GLLDS(gp, lp) __builtin_amdgcn_global_load_lds( \
  (const __attribute__((address_space(1))) uint32_t*)(const void*)(gp), \
  (__attribute__((address_space(3))) uint32_t*)(void*)(lp), 16, 0, 0)

// stage full K-tile: A 16KB (2 units) + B 8KB (1 unit)
#define STG(buf, kt) do { \
  GLLDS(A + (size_t)(m0 +       stRow) * IN_F + (kt) * BK2 + sl * 8, ldsb + (buf) * 24576 +         wid * 1024); \
  GLLDS(A + (size_t)(m0 + 128 + stRow) * IN_F + (kt) * BK2 + sl * 8, ldsb + (buf) * 24576 +  8192 + wid * 1024); \
  GLLDS(B + (size_t)(n0 +       stRow) * IN_F + (kt) * BK2 + sl * 8, ldsb + (buf) * 24576 + 16384 + wid * 1024); \
} while (0)

__global__ __launch_bounds__(512, 4) void gemm256(const ushort* __restrict__ A,
                                                  const ushort* __restrict__ B,
                                                  float* __restrict__ C, int M) {
  __shared__ ushort lds[24576];   // 48 KiB -> 2 blocks/CU (96 KiB of 160)
  char* ldsb = (char*)lds;

  const int nmt = M >> 8;                    // 32 M-tiles (BM=256)
  const int nwg = gridDim.x;                 // 1024
  int wg = blockIdx.x;
  if ((nwg & 7) == 0) wg = (wg & 7) * (nwg >> 3) + (wg >> 3);   // XCD swizzle (bijective)
  const int bn = wg / nmt;                   // 0..31 (BN=128)
  const int bm = wg % nmt;
  const int m0 = bm << 8, n0 = bn << 7;

  const int tid  = threadIdx.x;
  const int lane = tid & 63;
  const int wid  = tid >> 6;
  const int wm   = wid >> 1;                 // 0..3: A 64-row stripe
  const int wn   = wid & 1;                  // 0..1: B 64-col stripe

  // staging geometry: 512 threads cover 128 rows x 4 slots; slot pre-swizzled
  const int stRow = tid >> 2;                            // 0..127
  const int sl    = (tid & 3) ^ ((tid >> 3) & 3);        // phys = log ^ ((row>>1)&3)

  // fragment geometry (16x16x32): row = lane&15, k-slot = lane>>4; swizzle
  // term ((row>>1)&3) is lane-only (frag rows step by 16, wave bases by 64).
  const int frow = lane & 15;
  const int g    = lane >> 4;
  const int koff = ((g ^ ((frow >> 1) & 3)) << 4);

  f32x4 acc[4][4] = {};
  bf16x8 Af[4], Bf[4];

  // ---- prologue: stage tiles 0 and 1 (6 vmcnt units)
  STG(0, 0);
  STG(1, 1);

#pragma unroll 1
  for (int t = 0; t < NT2; ++t) {
    const int cur = t & 1;
    const char* aC = ldsb + cur * 24576;
    const char* bC = ldsb + cur * 24576 + 16384;

    // gate: own stage(t) landed, then block-wide
    if (t + 1 < NT2) VM3(); else VM0();
    BAR();

    // reads: 4 A-frags + 4 B-frags (b128, conflict-free per R9)
#pragma unroll
    for (int i = 0; i < 4; ++i)
      Af[i] = *(const bf16x8*)(aC + (wm * 64 + i * 16 + frow) * 64 + koff);
#pragma unroll
    for (int j = 0; j < 4; ++j)
      Bf[j] = *(const bf16x8*)(bC + (wn * 64 + j * 16 + frow) * 64 + koff);
    LGKM0();
    BAR();   // all waves' reads of tile t done -> cur buffer free for t+2

    if (t + 2 < NT2) STG(cur, t + 2);

    __builtin_amdgcn_s_setprio(1);
#pragma unroll
    for (int i = 0; i < 4; ++i)
#pragma unroll
      for (int j = 0; j < 4; ++j)
        acc[i][j] = __builtin_amdgcn_mfma_f32_16x16x32_bf16(Af[i], Bf[j], acc[i][j], 0, 0, 0);
    __builtin_amdgcn_s_setprio(0);
  }

  // ---- epilogue: C/D layout col=lane&15, row=(lane>>4)*4+reg [m89-verified]
  const int crow0 = m0 + wm * 64 + (g << 2);
  const int ccol0 = n0 + wn * 64 + frow;
#pragma unroll
  for (int mf = 0; mf < 4; ++mf)
#pragma unroll
    for (int nf = 0; nf < 4; ++nf)
#pragma unroll
      for (int q = 0; q < 4; ++q)
        C[(size_t)(crow0 + mf * 16 + q) * OUT_F + (ccol0 + nf * 16)] = acc[mf][nf][q];
}

// ---- fallback: naive f32, correct but slow ------------------------------
__global__ void naive_kernel(const float* __restrict__ x, const int* __restrict__ cw,
                             const float* __restrict__ sc, const float* __restrict__ of,
                             float* __restrict__ out, int M) {
  int idx = blockIdx.x * blockDim.x + threadIdx.x;
  if (idx >= M * OUT_F) return;
  int o = idx & (OUT_F - 1);
  int m = idx >> 12;
  const float* xr = x + (size_t)m * IN_F;
  const int*   wr = cw + (size_t)o * IN_F;
  float acc = 0.f;
  for (int gg = 0; gg < NGROUPS; ++gg) {
    float s = sc[o * NGROUPS + gg], off = of[o * NGROUPS + gg];
#pragma unroll 8
    for (int k = 0; k < 128; ++k) {
      int kk = (gg << 7) + k;
      acc += xr[kk] * ((float)wr[kk] * s - off);
    }
  }
  out[idx] = acc;
}

extern "C" void kernel_launch(void* const* d_in, const int* in_sizes, int n_in,
                              void* d_out, int out_size, void* d_ws, size_t ws_size,
                              hipStream_t stream) {
  const float* x  = (const float*)d_in[0];
  const int*   cw = (const int*)d_in[1];
  const float* sc = (const float*)d_in[2];
  const float* of = (const float*)d_in[3];
  float* out = (float*)d_out;
  const int M = in_sizes[0] / IN_F;   // 8192

  const size_t xb_bytes = (size_t)M * IN_F * 2;
  const size_t wb_bytes = (size_t)OUT_F * IN_F * 2;

  if (ws_size >= xb_bytes + wb_bytes && (M % 256) == 0) {
    ushort* xb = (ushort*)d_ws;
    ushort* wb = (ushort*)((char*)d_ws + xb_bytes);

    int n8 = (M * IN_F) / 8;
    cvt_x_kernel<<<(n8 + 255) / 256, 256, 0, stream>>>(x, xb, n8);

    int nw8 = (OUT_F * IN_F) / 8;
    dequant_w_kernel<<<(nw8 + 255) / 256, 256, 0, stream>>>(cw, sc, of, wb);

    dim3 grid((M / 256) * (OUT_F / 128));   // 32 * 32 = 1024 = 2 blocks/CU exactly
    gemm256<<<grid, 512, 0, stream>>>(xb, wb, out, M);
  } else {
    int total = M * OUT_F;
    naive_kernel<<<(total + 255) / 256, 256, 0, stream>>>(x, cw, sc, of, out, M);
  }
}

// Round 11
// 285.634 us; speedup vs baseline: 9.1741x; 1.4295x over previous
//
#include <hip/hip_runtime.h>
#include <stdint.h>

#define OUT_F 4096
#define IN_F  4096
#define NGROUPS 32
#define BK 64
#define NT (IN_F / BK)     // 64
#define NITER (NT / 2)     // 32

typedef __attribute__((ext_vector_type(4)))  float    f32x4;
typedef __attribute__((ext_vector_type(8)))  short    bf16x8;
typedef __attribute__((ext_vector_type(4)))  int      i32x4;
typedef __attribute__((ext_vector_type(4)))  uint32_t u32x4;

__device__ __forceinline__ ushort f2bf(float f) {
  union { float f; uint32_t u; } v; v.f = f;
  uint32_t r = v.u + 0x7FFFu + ((v.u >> 16) & 1u);
  return (ushort)(r >> 16);
}

// ---- kernel 1: x (f32) -> bf16, 8 elems/thread --------------------------
__global__ void cvt_x_kernel(const float* __restrict__ x, ushort* __restrict__ xb, int n8) {
  int i = blockIdx.x * blockDim.x + threadIdx.x;
  if (i >= n8) return;
  const f32x4* xp = (const f32x4*)x;
  f32x4 a = xp[2 * i], b = xp[2 * i + 1];
  u32x4 o;
  o.x = (uint32_t)f2bf(a.x) | ((uint32_t)f2bf(a.y) << 16);
  o.y = (uint32_t)f2bf(a.z) | ((uint32_t)f2bf(a.w) << 16);
  o.z = (uint32_t)f2bf(b.x) | ((uint32_t)f2bf(b.y) << 16);
  o.w = (uint32_t)f2bf(b.z) | ((uint32_t)f2bf(b.w) << 16);
  ((u32x4*)xb)[i] = o;
}

// ---- kernel 2: dequant weight -> bf16 [OUT_F][IN_F] ----------------------
__global__ void dequant_w_kernel(const int* __restrict__ cw,
                                 const float* __restrict__ sc,
                                 const float* __restrict__ of,
                                 ushort* __restrict__ wb) {
  int t = blockIdx.x * blockDim.x + threadIdx.x;
  int o  = t >> 9;
  int k0 = (t & 511) << 3;
  int g  = k0 >> 7;
  float s   = sc[o * NGROUPS + g];
  float off = of[o * NGROUPS + g];
  const i32x4* cp = (const i32x4*)(cw + (size_t)o * IN_F + k0);
  i32x4 c0 = cp[0], c1 = cp[1];
  u32x4 out;
  out.x = (uint32_t)f2bf((float)c0.x * s - off) | ((uint32_t)f2bf((float)c0.y * s - off) << 16);
  out.y = (uint32_t)f2bf((float)c0.z * s - off) | ((uint32_t)f2bf((float)c0.w * s - off) << 16);
  out.z = (uint32_t)f2bf((float)c1.x * s - off) | ((uint32_t)f2bf((float)c1.y * s - off) << 16);
  out.w = (uint32_t)f2bf((float)c1.z * s - off) | ((uint32_t)f2bf((float)c1.w * s - off) << 16);
  *(u32x4*)(wb + (size_t)o * IN_F + k0) = out;
}

// ---- kernel 3: 256x256, BK=64, 8-wave, 8-phase/2-K-tile (m201-exact sync)
// Identical to R7 EXCEPT: naked s_barrier (no compiler memory fences),
// un-clobbered lgkmcnt waits; only the vmcnt LEDGER gates keep "memory"
// (pins gl_lds issue order vs counted waits). Gives the backend scheduler
// m201's freedom to soften phase edges (hoist next reads into MFMA cluster).

#define BAR() __builtin_amdgcn_s_barrier()
#define LGKM0() asm volatile("s_waitcnt lgkmcnt(0)")
#define LGKM8() asm volatile("s_waitcnt lgkmcnt(8)")
#define VM4()   asm volatile("s_waitcnt vmcnt(4)" ::: "memory")
#define VM0()   asm volatile("s_waitcnt vmcnt(0)" ::: "memory")

#define GLLDS(gp, lp) __builtin_amdgcn_global_load_lds( \
  (const __attribute__((address_space(1))) uint32_t*)(const void*)(gp), \
  (__attribute__((address_space(3))) uint32_t*)(void*)(lp), 16, 0, 0)

// stage one 128x64 half-tile (2 gl_lds per thread)
#define STAGE_AH(buf, kt, h_) do { \
  _Pragma("unroll") for (int c_ = 0; c_ < 2; ++c_) \
    GLLDS(A + (size_t)(m0 + (h_) * 128 + c_ * 64 + stRow) * IN_F + (kt) * BK + sl * 8, \
          ldsb + (buf) * 65536 + (h_) * 16384 + c_ * 8192 + wid * 1024); \
} while (0)

#define STAGE_BH(buf, kt, h_) do { \
  _Pragma("unroll") for (int c_ = 0; c_ < 2; ++c_) \
    GLLDS(B + (size_t)(n0 + (h_) * 128 + c_ * 64 + stRow) * IN_F + (kt) * BK + sl * 8, \
          ldsb + (buf) * 65536 + 32768 + (h_) * 16384 + c_ * 8192 + wid * 1024); \
} while (0)

// read 4 A-frag-rows (one k-half H) / 2 B-frag-cols
#define RD_AH(dst, i0, base, H, OFF) do { \
  _Pragma("unroll") for (int i_ = 0; i_ < 4; ++i_) \
    dst[i_][H] = *(const bf16x8*)((base) + ((i0) + i_) * 2048 + (OFF)); \
} while (0)

#define RD_BH(dst, j0, base, H, OFF) do { \
  _Pragma("unroll") for (int j_ = 0; j_ < 2; ++j_) \
    dst[j_][H] = *(const bf16x8*)((base) + ((j0) + j_) * 2048 + (OFF)); \
} while (0)

// 16-MFMA quadrant (both k-halves)
#define MFMAQ16(I0, J0, Aset, Bset) do { \
  __builtin_amdgcn_s_setprio(1); \
  _Pragma("unroll") for (int h_ = 0; h_ < 2; ++h_) \
  _Pragma("unroll") for (int i_ = 0; i_ < 4; ++i_) \
  _Pragma("unroll") for (int j_ = 0; j_ < 2; ++j_) \
    acc[(I0) + i_][(J0) + j_] = __builtin_amdgcn_mfma_f32_16x16x32_bf16(Aset[i_][h_], Bset[j_][h_], acc[(I0) + i_][(J0) + j_], 0, 0, 0); \
  __builtin_amdgcn_s_setprio(0); \
} while (0)

__global__ __launch_bounds__(512, 2) void gemm256(const ushort* __restrict__ A,
                                                  const ushort* __restrict__ B,
                                                  float* __restrict__ C, int M) {
  __shared__ ushort lds[65536];   // 128 KiB
  char* ldsb = (char*)lds;

  const int nmt = M >> 8;
  const int nwg = gridDim.x;
  int wg = blockIdx.x;
  if ((nwg & 7) == 0) wg = (wg & 7) * (nwg >> 3) + (wg >> 3);   // XCD swizzle (bijective)
  const int bn = wg / nmt;
  const int bm = wg % nmt;
  const int m0 = bm << 8, n0 = bn << 8;

  const int tid  = threadIdx.x;
  const int lane = tid & 63;
  const int wid  = tid >> 6;
  const int wr   = wid >> 2;                 // A 128-row half
  const int wc   = wid & 3;                  // B 64-col stripe

  const int stRow = wid * 8 + (lane >> 3);
  const int sl    = (lane & 7) ^ (lane >> 3);

  const int frow = lane & 15;
  const int g    = lane >> 4;
  const int off0 = frow * 128 + (((g    ) ^ (lane & 7)) << 4);
  const int off1 = frow * 128 + (((4 + g) ^ (lane & 7)) << 4);

  f32x4 acc[8][4] = {};
  bf16x8 Ar[4][2], Bl[2][2], Bh[2][2];

  const char* aX = ldsb + wr * 16384;                      // buf0 A
  const char* bX = ldsb + 32768 + wc * 8192;               // buf0 B
  const char* aY = ldsb + 65536 + wr * 16384;              // buf1 A
  const char* bY = ldsb + 65536 + 32768 + wc * 8192;       // buf1 B

  // ---- prologue: tile0 (4 halves) + tile1 B (2 halves); vmcnt(4) lands tile0
  STAGE_AH(0, 0, 0); STAGE_AH(0, 0, 1);
  STAGE_BH(0, 0, 0); STAGE_BH(0, 0, 1);
  STAGE_BH(1, 1, 0); STAGE_BH(1, 1, 1);
  VM4();
  BAR();

#pragma unroll 1
  for (int j = 0; j < NITER; ++j) {
    const int tY = 2 * j + 1;
    const bool more = (j + 1 < NITER);

    // ================= tile X = 2j (buf0) =================
    // p1: rd 12; stage AloY; Q00
    RD_AH(Ar, 0, aX, 0, off0); RD_AH(Ar, 0, aX, 1, off1);
    RD_BH(Bl, 0, bX, 0, off0); RD_BH(Bl, 0, bX, 1, off1);
    STAGE_AH(1, tY, 0);
    LGKM8();
    BAR(); LGKM0();
    MFMAQ16(0, 0, Ar, Bl);
    BAR();

    // p2: rd 4; stage AhiY; Q01
    RD_BH(Bh, 2, bX, 0, off0); RD_BH(Bh, 2, bX, 1, off1);
    STAGE_AH(1, tY, 1);
    BAR(); LGKM0();
    MFMAQ16(0, 2, Ar, Bh);
    BAR();

    // p3: rd 8; stage BloX'; Q11
    RD_AH(Ar, 4, aX, 0, off0); RD_AH(Ar, 4, aX, 1, off1);
    if (more) STAGE_BH(0, tY + 1, 0);
    BAR(); LGKM0();
    MFMAQ16(4, 2, Ar, Bh);
    BAR();

    // p4: stage BhiX'; counted vmcnt (lands A(Y)+older); Q10
    if (more) { STAGE_BH(0, tY + 1, 1); VM4(); } else { VM0(); }
    BAR();
    MFMAQ16(4, 0, Ar, Bl);
    BAR();

    // ================= tile Y = 2j+1 (buf1) =================
    // p5: rd 12; stage AloX'; Q00
    RD_AH(Ar, 0, aY, 0, off0); RD_AH(Ar, 0, aY, 1, off1);
    RD_BH(Bl, 0, bY, 0, off0); RD_BH(Bl, 0, bY, 1, off1);
    if (more) STAGE_AH(0, tY + 1, 0);
    LGKM8();
    BAR(); LGKM0();
    MFMAQ16(0, 0, Ar, Bl);
    BAR();

    // p6: rd 4; stage AhiX'; Q01
    RD_BH(Bh, 2, bY, 0, off0); RD_BH(Bh, 2, bY, 1, off1);
    if (more) STAGE_AH(0, tY + 1, 1);
    BAR(); LGKM0();
    MFMAQ16(0, 2, Ar, Bh);
    BAR();

    // p7: rd 8; stage BloY'; Q11
    RD_AH(Ar, 4, aY, 0, off0); RD_AH(Ar, 4, aY, 1, off1);
    if (more) STAGE_BH(1, tY + 2, 0);
    BAR(); LGKM0();
    MFMAQ16(4, 2, Ar, Bh);
    BAR();

    // p8: stage BhiY'; counted vmcnt; Q10
    if (more) { STAGE_BH(1, tY + 2, 1); VM4(); }
    BAR();
    MFMAQ16(4, 0, Ar, Bl);
    BAR();
  }

  // ---- epilogue: C/D layout col=lane&15, row=(lane>>4)*4+reg [m89-verified]
  const int crow0 = m0 + wr * 128 + (g << 2);
  const int ccol0 = n0 + wc * 64 + frow;
#pragma unroll
  for (int mf = 0; mf < 8; ++mf)
#pragma unroll
    for (int nf = 0; nf < 4; ++nf)
#pragma unroll
      for (int q = 0; q < 4; ++q)
        C[(size_t)(crow0 + mf * 16 + q) * OUT_F + (ccol0 + nf * 16)] = acc[mf][nf][q];
}

// ---- fallback: naive f32, correct but slow ------------------------------
__global__ void naive_kernel(const float* __restrict__ x, const int* __restrict__ cw,
                             const float* __restrict__ sc, const float* __restrict__ of,
                             float* __restrict__ out, int M) {
  int idx = blockIdx.x * blockDim.x + threadIdx.x;
  if (idx >= M * OUT_F) return;
  int o = idx & (OUT_F - 1);
  int m = idx >> 12;
  const float* xr = x + (size_t)m * IN_F;
  const int*   wr = cw + (size_t)o * IN_F;
  float acc = 0.f;
  for (int gg = 0; gg < NGROUPS; ++gg) {
    float s = sc[o * NGROUPS + gg], off = of[o * NGROUPS + gg];
#pragma unroll 8
    for (int k = 0; k < 128; ++k) {
      int kk = (gg << 7) + k;
      acc += xr[kk] * ((float)wr[kk] * s - off);
    }
  }
  out[idx] = acc;
}

extern "C" void kernel_launch(void* const* d_in, const int* in_sizes, int n_in,
                              void* d_out, int out_size, void* d_ws, size_t ws_size,
                              hipStream_t stream) {
  const float* x  = (const float*)d_in[0];
  const int*   cw = (const int*)d_in[1];
  const float* sc = (const float*)d_in[2];
  const float* of = (const float*)d_in[3];
  float* out = (float*)d_out;
  const int M = in_sizes[0] / IN_F;   // 8192

  const size_t xb_bytes = (size_t)M * IN_F * 2;
  const size_t wb_bytes = (size_t)OUT_F * IN_F * 2;

  if (ws_size >= xb_bytes + wb_bytes && (M % 256) == 0) {
    ushort* xb = (ushort*)d_ws;
    ushort* wb = (ushort*)((char*)d_ws + xb_bytes);

    int n8 = (M * IN_F) / 8;
    cvt_x_kernel<<<(n8 + 255) / 256, 256, 0, stream>>>(x, xb, n8);

    int nw8 = (OUT_F * IN_F) / 8;
    dequant_w_kernel<<<(nw8 + 255) / 256, 256, 0, stream>>>(cw, sc, of, wb);

    dim3 grid((M / 256) * (OUT_F / 256));   // 32 * 16 = 512
    gemm256<<<grid, 512, 0, stream>>>(xb, wb, out, M);
  } else {
    int total = M * OUT_F;
    naive_kernel<<<(total + 255) / 256, 256, 0, stream>>>(x, cw, sc, of, out, M);
  }
}